// Round 1
// 559.173 us; speedup vs baseline: 1.0416x; 1.0416x over previous
//
#include <hip/hip_runtime.h>
#include <hip/hip_bf16.h>

// Problem: B=8, S=1024, D=512, H=8, DQ=DV=64, P=32
// Outputs: seq [B,S,D] fp32 (4194304) then probs [B,H,S,S] fp32 (67108864)

typedef __attribute__((ext_vector_type(8))) short short8;
typedef __attribute__((ext_vector_type(4))) short short4v;
typedef __attribute__((ext_vector_type(4))) float float4v;

#define MFMA16(a, b, c) __builtin_amdgcn_mfma_f32_16x16x32_bf16((a), (b), (c), 0, 0, 0)

__device__ inline unsigned short f2bf(float f) {
    unsigned u = __builtin_bit_cast(unsigned, f);
    unsigned r = (u + 0x7FFFu + ((u >> 16) & 1u)) >> 16;
    return (unsigned short)r;
}
__device__ inline float bf2f(unsigned short h) {
    unsigned u = ((unsigned)h) << 16;
    return __builtin_bit_cast(float, u);
}

// async global->LDS, 16B per lane. lds base must be wave-uniform; HW writes
// base + lane*16.
__device__ __forceinline__ void async16(const void* g, void* l) {
    __builtin_amdgcn_global_load_lds(
        (const __attribute__((address_space(1))) unsigned int*)(unsigned long long)g,
        (__attribute__((address_space(3))) unsigned int*)(unsigned)(unsigned long long)l,
        16, 0, 0);
}

// ---------------------------------------------------------------------------
// LayerNorm: x [8192,512] fp32 -> xn bf16. One wave per row.
__global__ __launch_bounds__(256) void ln_kernel(const float* __restrict__ x,
                                                 const float* __restrict__ g,
                                                 const float* __restrict__ b,
                                                 unsigned short* __restrict__ xn) {
    int wave = threadIdx.x >> 6;
    int lane = threadIdx.x & 63;
    size_t row = (size_t)blockIdx.x * 4 + wave;
    const float4* x4 = (const float4*)(x + row * 512);
    float4 v0 = x4[lane];
    float4 v1 = x4[lane + 64];
    float s = v0.x + v0.y + v0.z + v0.w + v1.x + v1.y + v1.z + v1.w;
    for (int o = 32; o; o >>= 1) s += __shfl_xor(s, o);
    float mu = s * (1.0f / 512.0f);
    float d0x = v0.x - mu, d0y = v0.y - mu, d0z = v0.z - mu, d0w = v0.w - mu;
    float d1x = v1.x - mu, d1y = v1.y - mu, d1z = v1.z - mu, d1w = v1.w - mu;
    float q = d0x * d0x + d0y * d0y + d0z * d0z + d0w * d0w +
              d1x * d1x + d1y * d1y + d1z * d1z + d1w * d1w;
    for (int o = 32; o; o >>= 1) q += __shfl_xor(q, o);
    float rs = rsqrtf(q * (1.0f / 512.0f) + 1e-5f);
    const float4* g4 = (const float4*)g;
    const float4* b4 = (const float4*)b;
    float4 g0 = g4[lane], g1 = g4[lane + 64];
    float4 b0 = b4[lane], b1 = b4[lane + 64];
    short4v o0, o1;
    o0[0] = (short)f2bf(d0x * rs * g0.x + b0.x);
    o0[1] = (short)f2bf(d0y * rs * g0.y + b0.y);
    o0[2] = (short)f2bf(d0z * rs * g0.z + b0.z);
    o0[3] = (short)f2bf(d0w * rs * g0.w + b0.w);
    o1[0] = (short)f2bf(d1x * rs * g1.x + b1.x);
    o1[1] = (short)f2bf(d1y * rs * g1.y + b1.y);
    o1[2] = (short)f2bf(d1z * rs * g1.z + b1.z);
    o1[3] = (short)f2bf(d1w * rs * g1.w + b1.w);
    *(short4v*)(xn + row * 512 + lane * 4) = o0;
    *(short4v*)(xn + row * 512 + 256 + lane * 4) = o1;
}

// ---------------------------------------------------------------------------
// Weight convert+transpose: W [k=512][n=512] fp32 -> WT [n][k] bf16.
__global__ __launch_bounds__(256) void wconv_kernel(const float* __restrict__ Wk,
                                                    const float* __restrict__ Wv,
                                                    const float* __restrict__ Wo,
                                                    unsigned short* __restrict__ WkT,
                                                    unsigned short* __restrict__ WvT,
                                                    unsigned short* __restrict__ WoT) {
    int i = blockIdx.x * 256 + threadIdx.x;
    const float* src = (blockIdx.y == 0) ? Wk : (blockIdx.y == 1) ? Wv : Wo;
    unsigned short* dst = (blockIdx.y == 0) ? WkT : (blockIdx.y == 1) ? WvT : WoT;
    int k = i >> 9, n = i & 511;
    dst[n * 512 + k] = f2bf(src[i]);
}

// ---------------------------------------------------------------------------
// bias[q,k] = (pos[q,k,:]·wp + bp) / sqrt(DQ)
__global__ __launch_bounds__(256) void bias_kernel(const float* __restrict__ pos,
                                                   const float* __restrict__ wp,
                                                   const float* __restrict__ bp,
                                                   float* __restrict__ biasS) {
    size_t idx = (size_t)blockIdx.x * 256 + threadIdx.x;
    const float4* p4 = (const float4*)pos + idx * 8;
    const float4* w4 = (const float4*)wp;
    float acc = 0.f;
#pragma unroll
    for (int j = 0; j < 8; j++) {
        float4 p = p4[j];
        float4 w = w4[j];
        acc += p.x * w.x + p.y * w.y + p.z * w.z + p.w * w.w;
    }
    biasS[idx] = (acc + bp[0]) * 0.125f;
}

// ---------------------------------------------------------------------------
// KV projection GEMM (m97 structure): 128x128 tile, BK=32, LDS via
// global_load_lds width 16. C = xn[8192,512] @ WT^T -> K (z=0) / Vt (z=1).
__global__ __launch_bounds__(256) void proj_kernel(const unsigned short* __restrict__ xn,
                                                   const unsigned short* __restrict__ WkT,
                                                   const unsigned short* __restrict__ WvT,
                                                   const float* __restrict__ bk,
                                                   const float* __restrict__ bv,
                                                   unsigned short* __restrict__ K,
                                                   unsigned short* __restrict__ Vt) {
    __shared__ unsigned short sa[128 * 32];
    __shared__ unsigned short sb[128 * 32];
    int z = blockIdx.z;
    const unsigned short* Bm = z ? WvT : WkT;
    const float* bias = z ? bv : bk;
    int m0 = blockIdx.y * 128, n0 = blockIdx.x * 128;
    int lane = threadIdx.x & 63, w = threadIdx.x >> 6;
    int l15 = lane & 15, quad = lane >> 4, q8 = quad * 8;
    int wm = w >> 1, wn = w & 1;
    int srow = w * 16 + (lane >> 2);  // staging row 0..63 (this wave's quarter)
    int scol = (lane & 3) * 8;        // staging k-elem offset
    float4v acc[4][4] = {};
    for (int k0 = 0; k0 < 512; k0 += 32) {
        __syncthreads();
        async16(xn + (size_t)(m0 + srow) * 512 + k0 + scol, &sa[w * 512]);
        async16(xn + (size_t)(m0 + 64 + srow) * 512 + k0 + scol, &sa[2048 + w * 512]);
        async16(Bm + (size_t)(n0 + srow) * 512 + k0 + scol, &sb[w * 512]);
        async16(Bm + (size_t)(n0 + 64 + srow) * 512 + k0 + scol, &sb[2048 + w * 512]);
        __syncthreads();
        short8 af[4], bf[4];
#pragma unroll
        for (int t = 0; t < 4; t++)
            af[t] = *(const short8*)&sa[(wm * 64 + t * 16 + l15) * 32 + q8];
#pragma unroll
        for (int t = 0; t < 4; t++)
            bf[t] = *(const short8*)&sb[(wn * 64 + t * 16 + l15) * 32 + q8];
#pragma unroll
        for (int mt = 0; mt < 4; mt++)
#pragma unroll
            for (int nt = 0; nt < 4; nt++)
                acc[mt][nt] = MFMA16(af[mt], bf[nt], acc[mt][nt]);
    }
#pragma unroll
    for (int mt = 0; mt < 4; mt++)
#pragma unroll
        for (int nt = 0; nt < 4; nt++)
#pragma unroll
            for (int r = 0; r < 4; r++) {
                int m = m0 + wm * 64 + mt * 16 + quad * 4 + r;
                int n = n0 + wn * 64 + nt * 16 + l15;
                float v = acc[mt][nt][r] + bias[n];
                int b = m >> 10, s = m & 1023;
                int h = n >> 6, d = n & 63;
                if (z == 0)
                    K[(((size_t)b * 8 + h) * 1024 + s) * 64 + d] = f2bf(v);
                else
                    Vt[(((size_t)b * 8 + h) * 64 + d) * 1024 + s] = f2bf(v);
            }
}

// ---------------------------------------------------------------------------
// Fused attention: 16 query rows per block (was 32). LDS = 16*1032*2B = 33KB
// -> 4 blocks/CU (16 waves/CU) instead of 2 (8 waves/CU). Grid doubles to
// 4096 blocks. Phase structure unchanged: scores (MFMA, A-frags in regs)
// -> +bias/mask -> LDS bf16 -> softmax -> probs (nontemporal global fp32)
// -> PV (MFMA) -> outb bf16.
__global__ __launch_bounds__(256) void attn_kernel(const unsigned short* __restrict__ K,
                                                   const unsigned short* __restrict__ Vt,
                                                   const float* __restrict__ biasS,
                                                   const float* __restrict__ wp,
                                                   const int* __restrict__ lens,
                                                   float* __restrict__ probs,
                                                   unsigned short* __restrict__ outb) {
    __shared__ unsigned short sc[16 * 1032];  // +8 pad per row
    int bid = blockIdx.x;
    int bh = bid >> 6, qt = bid & 63;
    int b = bh >> 3, h = bh & 7;
    int q0 = qt * 16;
    int lane = threadIdx.x & 63;
    int w = threadIdx.x >> 6;
    int l15 = lane & 15, quad = lane >> 4;
    int q8 = quad * 8;
    int len = lens[b];

    float swp = 0.f;
#pragma unroll
    for (int j = 0; j < 32; j++) swp += wp[j];
    float c1 = swp * 0.04419417382415922f;  // 1/(sqrt(H)*sqrt(DQ))

    const unsigned short* Kbh = K + (size_t)bh * 1024 * 64;
    short8 a00 = *(const short8*)(Kbh + (size_t)(q0 + l15) * 64 + q8);
    short8 a01 = *(const short8*)(Kbh + (size_t)(q0 + l15) * 64 + q8 + 32);

    // ---- phase 1: logits -> LDS bf16 ----
    for (int i = 0; i < 16; i++) {
        int n0 = (i * 4 + w) * 16;
        short8 b0 = *(const short8*)(Kbh + (size_t)(n0 + l15) * 64 + q8);
        short8 b1 = *(const short8*)(Kbh + (size_t)(n0 + l15) * 64 + q8 + 32);
        float4v acc0 = {};
        acc0 = MFMA16(a00, b0, acc0);
        acc0 = MFMA16(a01, b1, acc0);
        int key = n0 + l15;
        bool ok = key < len;
#pragma unroll
        for (int r = 0; r < 4; r++) {
            int row0 = quad * 4 + r;
            float lg0 = ok ? acc0[r] * c1 + biasS[(size_t)(q0 + row0) * 1024 + key] : -1e30f;
            sc[row0 * 1032 + key] = f2bf(lg0);
        }
    }
    __syncthreads();

    // ---- phase 2: row softmax; probs to global (nontemporal); bf16 to LDS ----
    for (int rr = 0; rr < 4; rr++) {
        int row = w * 4 + rr;
        float v[16];
        float mx = -1e30f;
#pragma unroll
        for (int j = 0; j < 16; j++) {
            v[j] = bf2f(sc[row * 1032 + lane + j * 64]);
            mx = fmaxf(mx, v[j]);
        }
        for (int o = 32; o; o >>= 1) mx = fmaxf(mx, __shfl_xor(mx, o));
        float s = 0.f;
#pragma unroll
        for (int j = 0; j < 16; j++) {
            v[j] = __expf(v[j] - mx);
            s += v[j];
        }
        for (int o = 32; o; o >>= 1) s += __shfl_xor(s, o);
        float inv = 1.0f / s;
        float* prow = probs + ((size_t)bh * 1024 + q0 + row) * 1024;
#pragma unroll
        for (int j = 0; j < 16; j++) {
            float p = v[j] * inv;
            sc[row * 1032 + lane + j * 64] = f2bf(p);
            __builtin_nontemporal_store(p, prow + lane + j * 64);
        }
    }
    __syncthreads();

    // ---- phase 3: out = probs @ V ----
    int nv = w * 16;
    const unsigned short* Vbh = Vt + (size_t)bh * 64 * 1024;
    float4v o0 = {};
    for (int ks = 0; ks < 32; ks++) {
        int k0 = ks * 32;
        short8 bb = *(const short8*)(Vbh + (size_t)(nv + l15) * 1024 + k0 + q8);
        short8 p0 = *(const short8*)&sc[l15 * 1032 + k0 + q8];
        o0 = MFMA16(p0, bb, o0);
    }
#pragma unroll
    for (int r = 0; r < 4; r++) {
        int row = quad * 4 + r;
        int qa = q0 + row;
        outb[((size_t)b * 1024 + qa) * 512 + h * 64 + nv + l15] = f2bf(o0[r]);
    }
}

// ---------------------------------------------------------------------------
// Out projection (m97 structure): seq = outb @ Wo + bo + x  (fp32 out)
__global__ __launch_bounds__(256) void oproj_kernel(const unsigned short* __restrict__ outb,
                                                    const unsigned short* __restrict__ WoT,
                                                    const float* __restrict__ bo,
                                                    const float* __restrict__ x,
                                                    float* __restrict__ seq) {
    __shared__ unsigned short sa[128 * 32];
    __shared__ unsigned short sb[128 * 32];
    int m0 = blockIdx.y * 128, n0 = blockIdx.x * 128;
    int lane = threadIdx.x & 63, w = threadIdx.x >> 6;
    int l15 = lane & 15, quad = lane >> 4, q8 = quad * 8;
    int wm = w >> 1, wn = w & 1;
    int srow = w * 16 + (lane >> 2);
    int scol = (lane & 3) * 8;
    float4v acc[4][4] = {};
    for (int k0 = 0; k0 < 512; k0 += 32) {
        __syncthreads();
        async16(outb + (size_t)(m0 + srow) * 512 + k0 + scol, &sa[w * 512]);
        async16(outb + (size_t)(m0 + 64 + srow) * 512 + k0 + scol, &sa[2048 + w * 512]);
        async16(WoT + (size_t)(n0 + srow) * 512 + k0 + scol, &sb[w * 512]);
        async16(WoT + (size_t)(n0 + 64 + srow) * 512 + k0 + scol, &sb[2048 + w * 512]);
        __syncthreads();
        short8 af[4], bf[4];
#pragma unroll
        for (int t = 0; t < 4; t++)
            af[t] = *(const short8*)&sa[(wm * 64 + t * 16 + l15) * 32 + q8];
#pragma unroll
        for (int t = 0; t < 4; t++)
            bf[t] = *(const short8*)&sb[(wn * 64 + t * 16 + l15) * 32 + q8];
#pragma unroll
        for (int mt = 0; mt < 4; mt++)
#pragma unroll
            for (int nt = 0; nt < 4; nt++)
                acc[mt][nt] = MFMA16(af[mt], bf[nt], acc[mt][nt]);
    }
#pragma unroll
    for (int mt = 0; mt < 4; mt++)
#pragma unroll
        for (int nt = 0; nt < 4; nt++)
#pragma unroll
            for (int r = 0; r < 4; r++) {
                int m = m0 + wm * 64 + mt * 16 + quad * 4 + r;
                int n = n0 + wn * 64 + nt * 16 + l15;
                seq[(size_t)m * 512 + n] = acc[mt][nt][r] + bo[n] + x[(size_t)m * 512 + n];
            }
}

// ---------------------------------------------------------------------------
extern "C" void kernel_launch(void* const* d_in, const int* in_sizes, int n_in,
                              void* d_out, int out_size, void* d_ws, size_t ws_size,
                              hipStream_t stream) {
    const float* x    = (const float*)d_in[0];
    const float* ln_g = (const float*)d_in[1];
    const float* ln_b = (const float*)d_in[2];
    const float* Wk   = (const float*)d_in[3];
    const float* bk   = (const float*)d_in[4];
    const float* Wv   = (const float*)d_in[5];
    const float* bv   = (const float*)d_in[6];
    const float* pos  = (const float*)d_in[7];
    const float* wp   = (const float*)d_in[8];
    const float* bp   = (const float*)d_in[9];
    const float* Wo   = (const float*)d_in[10];
    const float* bo   = (const float*)d_in[11];
    const int* lens   = (const int*)d_in[12];

    unsigned short* WkT  = (unsigned short*)d_ws;                 // 512KB
    unsigned short* WvT  = WkT + 512 * 512;                       // 512KB
    unsigned short* WoT  = WvT + 512 * 512;                       // 512KB
    unsigned short* xn   = WoT + 512 * 512;                       // 8MB
    unsigned short* Kb   = xn + (size_t)8192 * 512;               // 8MB
    unsigned short* Vt   = Kb + (size_t)64 * 1024 * 64;           // 8MB
    unsigned short* outb = Vt + (size_t)64 * 64 * 1024;           // 8MB
    float* biasS = (float*)(outb + (size_t)8192 * 512);           // 4MB

    float* seq = (float*)d_out;
    float* probs = seq + (size_t)8192 * 512;

    hipLaunchKernelGGL(wconv_kernel, dim3(1024, 3), dim3(256), 0, stream,
                       Wk, Wv, Wo, WkT, WvT, WoT);
    hipLaunchKernelGGL(ln_kernel, dim3(2048), dim3(256), 0, stream, x, ln_g, ln_b, xn);
    hipLaunchKernelGGL(bias_kernel, dim3(4096), dim3(256), 0, stream, pos, wp, bp, biasS);
    hipLaunchKernelGGL(proj_kernel, dim3(4, 64, 2), dim3(256), 0, stream,
                       xn, WkT, WvT, bk, bv, Kb, Vt);
    hipLaunchKernelGGL(attn_kernel, dim3(4096), dim3(256), 0, stream,
                       Kb, Vt, biasS, wp, lens, probs, outb);
    hipLaunchKernelGGL(oproj_kernel, dim3(4, 64), dim3(256), 0, stream,
                       outb, WoT, bo, x, seq);
}